// Round 23
// baseline (164.441 us; speedup 1.0000x reference)
//
#include <hip/hip_runtime.h>

typedef float  f4    __attribute__((ext_vector_type(4)));
typedef float  f32x4 __attribute__((ext_vector_type(4)));
typedef short  s16x8 __attribute__((ext_vector_type(8)));
typedef unsigned int u32x4 __attribute__((ext_vector_type(4)));

#define L_SEQ 2048
#define D4    16
#define NC4   512
#define RAD   128
#define NBH   48
#define TI    64
#define NTIL  (L_SEQ / TI)     // 32
#define NBLK  (NBH * NTIL)     // 1536
#define KROWS 320              // staged K cols [i0-128, i0+192)
#define HSTR  324              // band-buffer row stride in ushort (81 uint2)

// R19 (proven correct, TI=64, per-row-tile sweep masks) + ONE diff: the
// phase-3 sweep stores are nontemporal (the same single-diff that took
// R15 160.3 -> R21 144.0). TI=64 cuts K staging redundancy 9x -> 5x
// (~230 -> ~130 MB of read traffic contending with the write stream) and
// halves block generations.
//  Phase 1: stage K [i0-128, i0+192) as bf16 (swizzled units).
//  Phase 2: wave-pair p MFMAs row-tile p over its even/odd col-tiles -> regs.
//  Phase 2b: barrier; dump band-masked bf16 into sH (aliased over sK).
//  Phase 3: barrier; merged sweep, 8 complete rows per wave, nt stores;
//           mask per ROW-TILE: row il (p=il>>4) window
//           [max(i04+4p-32,0), min(i04+4p+36,512)).

__device__ __forceinline__ unsigned bf16rne(float f) {
    unsigned u = __float_as_uint(f);
    return (u + 0x7FFFu + ((u >> 16) & 1u)) >> 16;   // round-to-nearest-even
}

__global__ __launch_bounds__(512, 4)
void band_sweep(const float* __restrict__ Qg, const float* __restrict__ Kg,
                float* __restrict__ outg)
{
    // arena: phase 1-2 = sK (K rows as 8 16B-units, slot = si*8 + (u^(si&7)));
    // phase 2b-3 = sH (64 x HSTR ushort band buffer). 41472 B.
    __shared__ __align__(16) unsigned char smem[TI * HSTR * 2];
    u32x4*          sK = reinterpret_cast<u32x4*>(smem);
    unsigned short* sH = reinterpret_cast<unsigned short*>(smem);

    const int t  = threadIdx.x;
    const int id = blockIdx.x;
    // bijective XCD swizzle (NBLK % 8 == 0)
    const int swz = (id & 7) * (NBLK / 8) + (id >> 3);
    const int bh  = swz >> 5;
    const int i0  = (swz & (NTIL - 1)) * TI;
    const int i04 = i0 >> 2;

    const f4* __restrict__ K4 = reinterpret_cast<const f4*>(Kg) + (size_t)bh * L_SEQ * D4;
    const f4* __restrict__ Q4 = reinterpret_cast<const f4*>(Qg) + (size_t)bh * L_SEQ * D4;
    f4* __restrict__ O4       = reinterpret_cast<f4*>(outg)     + (size_t)bh * L_SEQ * NC4;

    const int kbase = i0 - RAD;

    // ---- phase 1: stage K rows [i0-128, i0+192) as bf16: 2560 units, 5/thread
#pragma unroll
    for (int itr = 0; itr < 5; ++itr) {
        const int s  = itr * 512 + t;
        const int si = s >> 3, u = s & 7;
        int row = kbase + si;
        row = row < 0 ? 0 : (row > L_SEQ - 1 ? L_SEQ - 1 : row);  // clamp; masked at dump
        const f4 a = K4[(size_t)row * D4 + 2 * u];
        const f4 b = K4[(size_t)row * D4 + 2 * u + 1];
        u32x4 w;
        w.x = bf16rne(a.x) | (bf16rne(a.y) << 16);
        w.y = bf16rne(a.z) | (bf16rne(a.w) << 16);
        w.z = bf16rne(b.x) | (bf16rne(b.y) << 16);
        w.w = bf16rne(b.z) | (bf16rne(b.w) << 16);
        sK[si * 8 + (u ^ (si & 7))] = w;
    }

    const int wv = t >> 6, l = t & 63, m = l & 15, g = l >> 4;
    const int p   = wv >> 1;            // row-tile 0..3 (16 rows each)
    const int par = wv & 1;             // even/odd col-tiles within the pair
    const int ib  = i0 + 16 * p;

    // Q A-frags (issued after staging loads; latency hides under the drain)
    s16x8 A1, A2;
    {
        const size_t qb = (size_t)(ib + m) * D4;
        const f4 qa = Q4[qb + 2 * g];
        const f4 qv = Q4[qb + 2 * g + 1];
        const f4 qc = Q4[qb + 8 + 2 * g];
        const f4 qd = Q4[qb + 8 + 2 * g + 1];
        u32x4 wa, wb;
        wa.x = bf16rne(qa.x) | (bf16rne(qa.y) << 16);
        wa.y = bf16rne(qa.z) | (bf16rne(qa.w) << 16);
        wa.z = bf16rne(qv.x) | (bf16rne(qv.y) << 16);
        wa.w = bf16rne(qv.z) | (bf16rne(qv.w) << 16);
        wb.x = bf16rne(qc.x) | (bf16rne(qc.y) << 16);
        wb.y = bf16rne(qc.z) | (bf16rne(qc.w) << 16);
        wb.z = bf16rne(qd.x) | (bf16rne(qd.y) << 16);
        wb.w = bf16rne(qd.z) | (bf16rne(qd.w) << 16);
        A1 = __builtin_bit_cast(s16x8, wa);
        A2 = __builtin_bit_cast(s16x8, wb);
    }
    __syncthreads();

    // ---- phase 2: MFMA -> band-masked values in statically-indexed regs.
    // Row-tile p: col-tiles c = 0..16 (cols [ib-128, ib+144)); even wave
    // c = 0,2,..,16 (9), odd wave c = 1,3,..,15 (8).
    f32x4 acc[9];
    const int ilb = 16 * p + 4 * g;
#pragma unroll
    for (int k = 0; k < 9; ++k) {
        const int c = par + 2 * k;
        if (c <= 16) {
            const int si = 16 * (p + c) + m;
            const u32x4 b1 = sK[si * 8 + ((g    ) ^ (si & 7))];
            const u32x4 b2 = sK[si * 8 + ((4 + g) ^ (si & 7))];
            f32x4 a0 = {0.f, 0.f, 0.f, 0.f};
            a0 = __builtin_amdgcn_mfma_f32_16x16x32_bf16(A1, __builtin_bit_cast(s16x8, b1), a0, 0, 0, 0);
            a0 = __builtin_amdgcn_mfma_f32_16x16x32_bf16(A2, __builtin_bit_cast(s16x8, b2), a0, 0, 0, 0);
            const int j = kbase + si;                   // global col (C col = lane&15)
#pragma unroll
            for (int r = 0; r < 4; ++r) {
                const int i = i0 + ilb + r;             // C row = 4*(lane>>4)+reg
                acc[k][r] = ((unsigned)(i - j + RAD) <= 2u * RAD) ? a0[r] : 0.f;
            }
        }
    }
    __syncthreads();   // all waves done reading sK

    // ---- phase 2b: dump band values as bf16 into sH (aliased over sK)
#pragma unroll
    for (int k = 0; k < 9; ++k) {
        const int c = par + 2 * k;
        if (c <= 16) {
            const int si = 16 * (p + c) + m;
#pragma unroll
            for (int r = 0; r < 4; ++r)
                sH[(ilb + r) * HSTR + si] = (unsigned short)bf16rne(acc[k][r]);
        }
    }
    __syncthreads();

    // ---- phase 3: merged linear full-row sweep (zeros + band), nt stores.
    // Mask per ROW-TILE: row il (tile p = il>>4) window chunks
    // [max(i04+4p-32,0), min(i04+4p+36,512)) -- exactly what tile p wrote.
    {
        const uint2* sU2 = reinterpret_cast<const uint2*>(sH);
        const int base = i04 - 32;                      // chunk -> band-col offset
#pragma unroll 1
        for (int rr = 0; rr < 8; ++rr) {
            const int il = wv * 8 + rr;                 // local row 0..63
            const int pr = il >> 4;                     // row-tile of this row
            int clo = i04 + 4 * pr - 32; clo = clo < 0 ? 0 : clo;
            int chi = i04 + 4 * pr + 36; chi = chi > NC4 ? NC4 : chi;
            f4* rowp = O4 + (size_t)(i0 + il) * NC4;
            const int ub = il * (HSTR / 4);             // uint2 row base = il*81
#pragma unroll
            for (int kk = 0; kk < 8; ++kk) {
                const int ch = kk * 64 + l;             // chunk 0..511, coalesced
                int off = ch - base;
                off = off < 0 ? 0 : (off > 79 ? 79 : off);   // clamp; selected below
                const uint2 w = sU2[ub + off];
                f4 v;
                v.x = __uint_as_float(w.x << 16);
                v.y = __uint_as_float(w.x & 0xffff0000u);
                v.z = __uint_as_float(w.y << 16);
                v.w = __uint_as_float(w.y & 0xffff0000u);
                if (!((ch >= clo) & (ch < chi))) v = f4{0.f, 0.f, 0.f, 0.f};
                __builtin_nontemporal_store(v, rowp + ch);
            }
        }
    }
}

extern "C" void kernel_launch(void* const* d_in, const int* in_sizes, int n_in,
                              void* d_out, int out_size, void* d_ws, size_t ws_size,
                              hipStream_t stream) {
    const float* Q = (const float*)d_in[0];
    const float* K = (const float*)d_in[1];
    float* out = (float*)d_out;
    band_sweep<<<NBLK, 512, 0, stream>>>(Q, K, out);
}

// Round 24
// 143.986 us; speedup vs baseline: 1.1421x; 1.1421x over previous
//
#include <hip/hip_runtime.h>

typedef float  f4    __attribute__((ext_vector_type(4)));
typedef float  f32x4 __attribute__((ext_vector_type(4)));
typedef short  s16x8 __attribute__((ext_vector_type(8)));
typedef unsigned int u32x4 __attribute__((ext_vector_type(4)));

#define L_SEQ 2048
#define D4    16
#define NC4   512
#define RAD   128
#define NBH   48
#define TI    32
#define NTIL  (L_SEQ / TI)     // 64
#define NBLK  (NBH * NTIL)     // 3072
#define KROWS 288              // staged K rows = window cols [i0-128, i0+160)
#define HSTR  296              // band-buffer row stride in ushort (74 uint2)

// R21 champion restored (144.0us): R15 compute-then-sweep + nontemporal
// sweep stores. Validated levers: (1) 100% of output traffic is fill-shaped
// -- each wave writes complete rows linearly, 1KB/wave-inst, each row
// written exactly once (R15: 195->160); (2) nt stores keep the write-once
// output from churning L2 and evicting the K/Q working set (R21: 160->144).
// All other axes (occupancy, LDS traffic, tile size, pipelining, role
// split/mix, phase order) tested and neutral-or-worse.
//  Phase 1: stage K window [i0-128,i0+160) as bf16 in LDS (swizzled).
//  Phase 2: MFMA 2 row-tiles x 18 col-tiles -> band-masked bf16 into sH.
//  Phase 3: every wave writes 8 COMPLETE rows linearly, zeros + band
//           merged from LDS, all nontemporal.

__device__ __forceinline__ unsigned bf16rne(float f) {
    unsigned u = __float_as_uint(f);
    return (u + 0x7FFFu + ((u >> 16) & 1u)) >> 16;   // round-to-nearest-even
}

__global__ __launch_bounds__(256, 2)
void band_sweep(const float* __restrict__ Qg, const float* __restrict__ Kg,
                float* __restrict__ outg)
{
    // K rows as 8 16B-units (8 bf16, d-ascending); slot = si*8 + (u ^ (si&7))
    __shared__ u32x4 sK[KROWS * 8];            // 36864 B
    __shared__ unsigned short sH[TI * HSTR];   // 18944 B (total 55808 -> 2 blocks/CU)

    const int t  = threadIdx.x;
    const int id = blockIdx.x;
    // bijective XCD swizzle (NBLK % 8 == 0)
    const int swz = (id & 7) * (NBLK / 8) + (id >> 3);
    const int bh  = swz >> 6;
    const int i0  = (swz & (NTIL - 1)) * TI;
    const int i04 = i0 >> 2;

    const f4* __restrict__ K4 = reinterpret_cast<const f4*>(Kg) + (size_t)bh * L_SEQ * D4;
    const f4* __restrict__ Q4 = reinterpret_cast<const f4*>(Qg) + (size_t)bh * L_SEQ * D4;
    f4* __restrict__ O4       = reinterpret_cast<f4*>(outg)     + (size_t)bh * L_SEQ * NC4;

    const int kbase = i0 - RAD;

    // ---- phase 1: stage K rows [i0-128, i0+160) as bf16: 2304 units, 9/thread
#pragma unroll 3
    for (int itr = 0; itr < 9; ++itr) {
        const int s  = itr * 256 + t;
        const int si = s >> 3, u = s & 7;
        int row = kbase + si;
        row = row < 0 ? 0 : (row > L_SEQ - 1 ? L_SEQ - 1 : row);  // clamp; masked at dump
        const f4 a = K4[(size_t)row * D4 + 2 * u];
        const f4 b = K4[(size_t)row * D4 + 2 * u + 1];
        u32x4 w;
        w.x = bf16rne(a.x) | (bf16rne(a.y) << 16);
        w.y = bf16rne(a.z) | (bf16rne(a.w) << 16);
        w.z = bf16rne(b.x) | (bf16rne(b.y) << 16);
        w.w = bf16rne(b.z) | (bf16rne(b.w) << 16);
        sK[si * 8 + (u ^ (si & 7))] = w;
    }

    const int wv = t >> 6, l = t & 63, m = l & 15, g = l >> 4;
    const int rt = wv & 1;              // row-tile (0/1); wave pair splits col-tiles
    const int ib = i0 + 16 * rt;

    // Q A-frags (issued after staging loads; latency hides under the drain)
    s16x8 A1, A2;
    {
        const size_t qb = (size_t)(ib + m) * D4;
        const f4 qa = Q4[qb + 2 * g];
        const f4 qv = Q4[qb + 2 * g + 1];
        const f4 qc = Q4[qb + 8 + 2 * g];
        const f4 qd = Q4[qb + 8 + 2 * g + 1];
        u32x4 wa, wb;
        wa.x = bf16rne(qa.x) | (bf16rne(qa.y) << 16);
        wa.y = bf16rne(qa.z) | (bf16rne(qa.w) << 16);
        wa.z = bf16rne(qv.x) | (bf16rne(qv.y) << 16);
        wa.w = bf16rne(qv.z) | (bf16rne(qv.w) << 16);
        wb.x = bf16rne(qc.x) | (bf16rne(qc.y) << 16);
        wb.y = bf16rne(qc.z) | (bf16rne(qc.w) << 16);
        wb.z = bf16rne(qd.x) | (bf16rne(qd.y) << 16);
        wb.w = bf16rne(qd.z) | (bf16rne(qd.w) << 16);
        A1 = __builtin_bit_cast(s16x8, wa);
        A2 = __builtin_bit_cast(s16x8, wb);
    }
    __syncthreads();

    // ---- phase 2: MFMA -> band-masked bf16 values into sH
    {
        const int ilb = 16 * rt + 4 * g;
#pragma unroll 1
        for (int k = 0; k < 9; ++k) {
            const int c  = (wv >> 1) + 2 * k;           // col-tile 0..17
            const int si = 16 * c + m;
            const u32x4 b1 = sK[si * 8 + ((g    ) ^ (si & 7))];
            const u32x4 b2 = sK[si * 8 + ((4 + g) ^ (si & 7))];
            f32x4 acc = {0.f, 0.f, 0.f, 0.f};
            acc = __builtin_amdgcn_mfma_f32_16x16x32_bf16(A1, __builtin_bit_cast(s16x8, b1), acc, 0, 0, 0);
            acc = __builtin_amdgcn_mfma_f32_16x16x32_bf16(A2, __builtin_bit_cast(s16x8, b2), acc, 0, 0, 0);
            const int j = kbase + si;                   // global col (C col = lane&15)
#pragma unroll
            for (int r = 0; r < 4; ++r) {
                const int i = i0 + ilb + r;             // C row = 4*(lane>>4)+reg
                const float v = ((unsigned)(i - j + RAD) <= 2u * RAD) ? acc[r] : 0.f;
                sH[(ilb + r) * HSTR + si] = (unsigned short)bf16rne(v);
            }
        }
    }
    __syncthreads();

    // ---- phase 3: linear full-row sweep (zeros + band), nt stores, 1KB/wave-inst
    {
        const uint2* sU2 = reinterpret_cast<const uint2*>(sH);
        const int clo  = i04 - 32 < 0 ? 0 : i04 - 32;   // window chunk range
        const int chi  = i04 + 40 > NC4 ? NC4 : i04 + 40;
        const int base = i04 - 32;                      // chunk -> band-col offset
#pragma unroll 1
        for (int rr = 0; rr < 8; ++rr) {
            const int il = wv * 8 + rr;                 // local row 0..31
            f4* rowp = O4 + (size_t)(i0 + il) * NC4;
            const int ub = il * (HSTR / 4);             // uint2 row base = il*74
#pragma unroll
            for (int kk = 0; kk < 8; ++kk) {
                const int ch = kk * 64 + l;             // chunk 0..511, coalesced
                int off = ch - base;
                off = off < 0 ? 0 : (off > 71 ? 71 : off);   // clamp; selected below
                const uint2 w = sU2[ub + off];
                f4 v;
                v.x = __uint_as_float(w.x << 16);
                v.y = __uint_as_float(w.x & 0xffff0000u);
                v.z = __uint_as_float(w.y << 16);
                v.w = __uint_as_float(w.y & 0xffff0000u);
                if (!((ch >= clo) & (ch < chi))) v = f4{0.f, 0.f, 0.f, 0.f};
                __builtin_nontemporal_store(v, rowp + ch);
            }
        }
    }
}

extern "C" void kernel_launch(void* const* d_in, const int* in_sizes, int n_in,
                              void* d_out, int out_size, void* d_ws, size_t ws_size,
                              hipStream_t stream) {
    const float* Q = (const float*)d_in[0];
    const float* K = (const float*)d_in[1];
    float* out = (float*)d_out;
    band_sweep<<<NBLK, 256, 0, stream>>>(Q, K, out);
}